// Round 1
// baseline (254.430 us; speedup 1.0000x reference)
//
#include <hip/hip_runtime.h>

#define TPB 256
#define CSH 10                 // nodes per dst bucket = 1024
#define CN 1024
#define NBC_MAX 128
#define STILE 8192
#define EPT (STILE / TPB)

// fixed-point packing: value -> (int)rn(v*SCALE) + BIAS, two per u64
#define B20 1048576            // bias 2^20
#define S1F 131072.0f          // layer-1 scale 2^17
#define S2F 8192.0f            // layer-2 scale 2^13

typedef unsigned long long u64;

__device__ __forceinline__ unsigned enc_fx(float v, float scale) {
    int xi = __float2int_rn(v * scale);
    xi = max(-(B20 - 1), min(B20 - 1, xi));
    return (unsigned)(xi + B20);
}

__global__ void k_zero(int* __restrict__ p, int n) {
    int i = blockIdx.x * blockDim.x + threadIdx.x;
    if (i < n) p[i] = 0;
}

// per-tile bucket grouping, in place in the tile's own packed segment.
// packed = (src<<CSH)|(dst&(CN-1)); TRANSPOSED directory chunklT/chunkpT[b*ntiles+t]
// (bucket-major so the walkers' per-wave directory preload is coalesced).
__global__ void k_passCk(const int* __restrict__ src, const int* __restrict__ dst,
                         unsigned* __restrict__ packed, int* __restrict__ chunklT,
                         int* __restrict__ chunkpT, int E, int NBC, int ntiles) {
    __shared__ unsigned stage[STILE];          // 32 KB
    __shared__ int cnt[NBC_MAX], lb[NBC_MAX];
    int tb = blockIdx.x * STILE;
    int te = min(E, tb + STILE);
    if (threadIdx.x < NBC_MAX) cnt[threadIdx.x] = 0;
    __syncthreads();
    unsigned pk[EPT];
    int br[EPT];   // bucket | rank<<7  (bucket < 128)
#pragma unroll
    for (int u = 0; u < EPT; u++) {
        int i = tb + u * TPB + (int)threadIdx.x;
        br[u] = -1;
        if (i < te) {
            int d = dst[i];
            int b = d >> CSH;
            pk[u] = ((unsigned)src[i] << CSH) | (unsigned)(d & (CN - 1));
            int r = atomicAdd(&cnt[b], 1);     // rank doubles as count
            br[u] = b | (r << 7);
        }
    }
    __syncthreads();
    if (threadIdx.x < (unsigned)NBC) {
        int b = threadIdx.x;
        int sum = 0;
        for (int j = 0; j < b; j++) sum += cnt[j];   // same-addr broadcast reads
        lb[b] = sum;
        chunklT[(size_t)b * ntiles + blockIdx.x] = cnt[b];
        chunkpT[(size_t)b * ntiles + blockIdx.x] = tb + sum;  // deterministic position
    }
    __syncthreads();
#pragma unroll
    for (int u = 0; u < EPT; u++) {
        if (br[u] >= 0) {
            int b = br[u] & (NBC_MAX - 1);
            stage[lb[b] + (br[u] >> 7)] = pk[u];
        }
    }
    __syncthreads();
    for (int i = threadIdx.x; i < te - tb; i += TPB)  // fully coalesced flush
        packed[tb + i] = stage[i];
}

// ---- chunk-walk helpers: each wave owns a contiguous, balanced tile range;
// its directory is preloaded into lane registers (1 coalesced load) and
// broadcast per chunk via shfl; chunks processed 2-at-a-time with unguarded
// address-clamped loads so 4 independent load->gather->atomic chains overlap.

// degrees: per (bucket, split) block
__global__ void k_degk(const unsigned* __restrict__ packed, const int* __restrict__ chunklT,
                       const int* __restrict__ chunkpT, int* __restrict__ deg,
                       int SD, int ntiles, int E, int N) {
    __shared__ int cnt[CN];
    for (int i = threadIdx.x; i < CN; i += TPB) cnt[i] = 0;
    __syncthreads();
    int b = blockIdx.x / SD, s = blockIdx.x - b * SD;
    int wv = threadIdx.x >> 6, lane = threadIdx.x & 63;
    int W = SD * 4, widx = s * 4 + wv;
    int base = ntiles / W, rem = ntiles - base * W;
    int q0 = widx * base + min(widx, rem);
    int nch = base + (widx < rem ? 1 : 0);
    const int* cl = chunklT + (size_t)b * ntiles;
    const int* cp = chunkpT + (size_t)b * ntiles;
    for (int jb = 0; jb < nch; jb += 64) {
        int mylen = 0, mypos = 0;
        if (jb + lane < nch) {
            mylen = cl[q0 + jb + lane];
            mypos = cp[q0 + jb + lane];
        }
        int jcnt = min(64, nch - jb);
        for (int j = 0; j < jcnt; j += 2) {
            int len0 = __shfl(mylen, j), pos0 = __shfl(mypos, j);
            int len1 = 0, pos1 = 0;
            if (j + 1 < jcnt) { len1 = __shfl(mylen, j + 1); pos1 = __shfl(mypos, j + 1); }
            unsigned pk0a = packed[min(pos0 + lane,      E - 1)];
            unsigned pk0b = packed[min(pos0 + 64 + lane, E - 1)];
            unsigned pk1a = packed[min(pos1 + lane,      E - 1)];
            unsigned pk1b = packed[min(pos1 + 64 + lane, E - 1)];
            if (lane < len0)      atomicAdd(&cnt[pk0a & (CN - 1)], 1);
            if (64 + lane < len0) atomicAdd(&cnt[pk0b & (CN - 1)], 1);
            if (lane < len1)      atomicAdd(&cnt[pk1a & (CN - 1)], 1);
            if (64 + lane < len1) atomicAdd(&cnt[pk1b & (CN - 1)], 1);
            for (int i = 128 + lane; i < len0; i += 64)   // rare tail
                atomicAdd(&cnt[packed[pos0 + i] & (CN - 1)], 1);
            for (int i = 128 + lane; i < len1; i += 64)
                atomicAdd(&cnt[packed[pos1 + i] & (CN - 1)], 1);
        }
    }
    __syncthreads();
    int node0 = b << CSH;
    for (int i = threadIdx.x; i < CN; i += TPB)
        if (cnt[i] && node0 + i < N) atomicAdd(&deg[node0 + i], cnt[i]);
}

// xs = x * rsqrt(deg+1) (float4 self-term) and encoded uint4 for gathers
__global__ void k_prepv(const float* __restrict__ x, const int* __restrict__ deg,
                        float* __restrict__ xs, unsigned* __restrict__ xse, int N) {
    int v = blockIdx.x * blockDim.x + threadIdx.x;
    if (v >= N) return;
    float di = rsqrtf((float)(deg[v] + 1));
    float4 xv = ((const float4*)x)[v];
    xv.x *= di; xv.y *= di; xv.z *= di; xv.w *= di;
    ((float4*)xs)[v] = xv;
    uint4 e;
    e.x = enc_fx(xv.x, S1F); e.y = enc_fx(xv.y, S1F);
    e.z = enc_fx(xv.z, S1F); e.w = enc_fx(xv.w, S1F);
    ((uint4*)xse)[v] = e;
}

#define AGG1_AT(pkv, gv) { int n_ = (int)((pkv) & (CN - 1)) * 3; \
    atomicAdd(&acc[n_],     (u64)(gv).x | ((u64)(gv).y << 32)); \
    atomicAdd(&acc[n_ + 1], (u64)(gv).z | ((u64)(gv).w << 32)); }

// layer-1 edge pass: 2 packed u64 LDS atomics per edge; pipelined chunk walk
__global__ void k_agg1k(const unsigned* __restrict__ packed, const int* __restrict__ chunklT,
                        const int* __restrict__ chunkpT, const unsigned* __restrict__ xse,
                        u64* __restrict__ partial1, int S1, int ntiles, int E) {
    __shared__ u64 acc[CN * 3];   // stride 3 u64 to spread banks; 24 KB
    for (int i = threadIdx.x; i < CN * 3; i += TPB) acc[i] = 0ULL;
    __syncthreads();
    int b = blockIdx.x / S1, s = blockIdx.x - b * S1;
    int wv = threadIdx.x >> 6, lane = threadIdx.x & 63;
    int W = S1 * 4, widx = s * 4 + wv;
    int base = ntiles / W, rem = ntiles - base * W;
    int q0 = widx * base + min(widx, rem);
    int nch = base + (widx < rem ? 1 : 0);
    const int* cl = chunklT + (size_t)b * ntiles;
    const int* cp = chunkpT + (size_t)b * ntiles;
    const uint4* xse4 = (const uint4*)xse;
    for (int jb = 0; jb < nch; jb += 64) {
        int mylen = 0, mypos = 0;
        if (jb + lane < nch) {
            mylen = cl[q0 + jb + lane];
            mypos = cp[q0 + jb + lane];
        }
        int jcnt = min(64, nch - jb);
        for (int j = 0; j < jcnt; j += 2) {
            int len0 = __shfl(mylen, j), pos0 = __shfl(mypos, j);
            int len1 = 0, pos1 = 0;
            if (j + 1 < jcnt) { len1 = __shfl(mylen, j + 1); pos1 = __shfl(mypos, j + 1); }
            unsigned pk0a = packed[min(pos0 + lane,      E - 1)];
            unsigned pk0b = packed[min(pos0 + 64 + lane, E - 1)];
            unsigned pk1a = packed[min(pos1 + lane,      E - 1)];
            unsigned pk1b = packed[min(pos1 + 64 + lane, E - 1)];
            uint4 g0a = xse4[pk0a >> CSH];
            uint4 g0b = xse4[pk0b >> CSH];
            uint4 g1a = xse4[pk1a >> CSH];
            uint4 g1b = xse4[pk1b >> CSH];
            if (lane < len0)      AGG1_AT(pk0a, g0a);
            if (64 + lane < len0) AGG1_AT(pk0b, g0b);
            if (lane < len1)      AGG1_AT(pk1a, g1a);
            if (64 + lane < len1) AGG1_AT(pk1b, g1b);
            for (int i = 128 + lane; i < len0; i += 64) {  // rare tail
                unsigned pk = packed[pos0 + i];
                uint4 g = xse4[pk >> CSH];
                AGG1_AT(pk, g);
            }
            for (int i = 128 + lane; i < len1; i += 64) {
                unsigned pk = packed[pos1 + i];
                uint4 g = xse4[pk >> CSH];
                AGG1_AT(pk, g);
            }
        }
    }
    __syncthreads();
    u64* p = partial1 + (size_t)blockIdx.x * (CN * 2);
    for (int i = threadIdx.x; i < CN * 2; i += TPB)
        p[i] = acc[(i >> 1) * 3 + (i & 1)];
}

// layer-1 combine: decode fixed-point, +self, *dis -> MLP -> hs2 (float + encoded)
__global__ void k_comb1q(const u64* __restrict__ partial1,
                         const float* __restrict__ xs, const int* __restrict__ deg,
                         const float* __restrict__ W1, const float* __restrict__ b1,
                         const float* __restrict__ W2,
                         float* __restrict__ hs2f, unsigned* __restrict__ hs2e,
                         int S1, int N) {
    __shared__ float w1[64], w2[32], bb[16];
    if (threadIdx.x < 64) w1[threadIdx.x] = W1[threadIdx.x];
    if (threadIdx.x < 32) w2[threadIdx.x] = W2[threadIdx.x];
    if (threadIdx.x < 16) bb[threadIdx.x] = b1[threadIdx.x];
    __syncthreads();
    int v = blockIdx.x * blockDim.x + threadIdx.x;
    if (v >= N) return;
    int b = v >> CSH, lv = v & (CN - 1);
    u64 a01 = 0, a23 = 0;
    for (int s = 0; s < S1; s++) {
        const u64* q = partial1 + ((size_t)(b * S1 + s) * CN + lv) * 2;
        a01 += q[0];
        a23 += q[1];
    }
    int dg = deg[v];
    long long bias = (long long)dg << 20;
    const float inv = 1.0f / S1F;
    float f0 = (float)((long long)(a01 & 0xffffffffULL) - bias) * inv;
    float f1 = (float)((long long)(a01 >> 32) - bias) * inv;
    float f2 = (float)((long long)(a23 & 0xffffffffULL) - bias) * inv;
    float f3 = (float)((long long)(a23 >> 32) - bias) * inv;
    float4 self = ((const float4*)xs)[v];
    float di = rsqrtf((float)(dg + 1));
    float v0 = (f0 + self.x) * di, v1 = (f1 + self.y) * di;
    float v2 = (f2 + self.z) * di, v3 = (f3 + self.w) * di;
    float s0 = 0.f, s1 = 0.f;
#pragma unroll
    for (int j = 0; j < 16; j++) {
        float h = v0 * w1[j] + v1 * w1[16 + j] + v2 * w1[32 + j] + v3 * w1[48 + j] + bb[j];
        h = fmaxf(h, 0.0f);
        s0 += h * w2[2 * j];
        s1 += h * w2[2 * j + 1];
    }
    s0 *= di; s1 *= di;
    ((float2*)hs2f)[v] = make_float2(s0, s1);
    uint2 e;
    e.x = enc_fx(s0, S2F);
    e.y = enc_fx(s1, S2F);
    ((uint2*)hs2e)[v] = e;
}

// layer-2 edge pass: 1 packed u64 LDS atomic per edge; pipelined chunk walk
__global__ void k_agg2k(const unsigned* __restrict__ packed, const int* __restrict__ chunklT,
                        const int* __restrict__ chunkpT, const unsigned* __restrict__ hs2e,
                        u64* __restrict__ partial2, int S2, int ntiles, int E) {
    __shared__ u64 acc[CN];   // 8 KB
    for (int i = threadIdx.x; i < CN; i += TPB) acc[i] = 0ULL;
    __syncthreads();
    int b = blockIdx.x / S2, s = blockIdx.x - b * S2;
    int wv = threadIdx.x >> 6, lane = threadIdx.x & 63;
    int W = S2 * 4, widx = s * 4 + wv;
    int base = ntiles / W, rem = ntiles - base * W;
    int q0 = widx * base + min(widx, rem);
    int nch = base + (widx < rem ? 1 : 0);
    const int* cl = chunklT + (size_t)b * ntiles;
    const int* cp = chunkpT + (size_t)b * ntiles;
    const uint2* h2 = (const uint2*)hs2e;
    for (int jb = 0; jb < nch; jb += 64) {
        int mylen = 0, mypos = 0;
        if (jb + lane < nch) {
            mylen = cl[q0 + jb + lane];
            mypos = cp[q0 + jb + lane];
        }
        int jcnt = min(64, nch - jb);
        for (int j = 0; j < jcnt; j += 2) {
            int len0 = __shfl(mylen, j), pos0 = __shfl(mypos, j);
            int len1 = 0, pos1 = 0;
            if (j + 1 < jcnt) { len1 = __shfl(mylen, j + 1); pos1 = __shfl(mypos, j + 1); }
            unsigned pk0a = packed[min(pos0 + lane,      E - 1)];
            unsigned pk0b = packed[min(pos0 + 64 + lane, E - 1)];
            unsigned pk1a = packed[min(pos1 + lane,      E - 1)];
            unsigned pk1b = packed[min(pos1 + 64 + lane, E - 1)];
            uint2 g0a = h2[pk0a >> CSH];
            uint2 g0b = h2[pk0b >> CSH];
            uint2 g1a = h2[pk1a >> CSH];
            uint2 g1b = h2[pk1b >> CSH];
            if (lane < len0)
                atomicAdd(&acc[pk0a & (CN - 1)], (u64)g0a.x | ((u64)g0a.y << 32));
            if (64 + lane < len0)
                atomicAdd(&acc[pk0b & (CN - 1)], (u64)g0b.x | ((u64)g0b.y << 32));
            if (lane < len1)
                atomicAdd(&acc[pk1a & (CN - 1)], (u64)g1a.x | ((u64)g1a.y << 32));
            if (64 + lane < len1)
                atomicAdd(&acc[pk1b & (CN - 1)], (u64)g1b.x | ((u64)g1b.y << 32));
            for (int i = 128 + lane; i < len0; i += 64) {  // rare tail
                unsigned pk = packed[pos0 + i];
                uint2 g = h2[pk >> CSH];
                atomicAdd(&acc[pk & (CN - 1)], (u64)g.x | ((u64)g.y << 32));
            }
            for (int i = 128 + lane; i < len1; i += 64) {
                unsigned pk = packed[pos1 + i];
                uint2 g = h2[pk >> CSH];
                atomicAdd(&acc[pk & (CN - 1)], (u64)g.x | ((u64)g.y << 32));
            }
        }
    }
    __syncthreads();
    u64* p = partial2 + (size_t)blockIdx.x * CN;
    for (int i = threadIdx.x; i < CN; i += TPB) p[i] = acc[i];
}

// layer-2 combine: decode, +self, *dis, +bias -> out
__global__ void k_comb2q(const u64* __restrict__ partial2,
                         const float* __restrict__ hs2f, const int* __restrict__ deg,
                         const float* __restrict__ b2, float* __restrict__ out,
                         int S2, int N) {
    int v = blockIdx.x * blockDim.x + threadIdx.x;
    if (v >= N) return;
    int b = v >> CSH, lv = v & (CN - 1);
    u64 t = 0;
    for (int s = 0; s < S2; s++)
        t += partial2[(size_t)(b * S2 + s) * CN + lv];
    int dg = deg[v];
    long long bias = (long long)dg << 20;
    const float inv = 1.0f / S2F;
    float f0 = (float)((long long)(t & 0xffffffffULL) - bias) * inv;
    float f1 = (float)((long long)(t >> 32) - bias) * inv;
    float2 self = ((const float2*)hs2f)[v];
    float di = rsqrtf((float)(dg + 1));
    ((float2*)out)[v] = make_float2((f0 + self.x) * di + b2[0],
                                    (f1 + self.y) * di + b2[1]);
}

// ---------------- fallback (R1 atomic pipeline) ----------------

__global__ void k_deg_fb(const int* __restrict__ dst, int* __restrict__ deg, int E) {
    int i = blockIdx.x * blockDim.x + threadIdx.x;
    if (i < E) atomicAdd(&deg[dst[i]], 1);
}
__global__ void k_dis_fb(const int* __restrict__ deg, float* __restrict__ dis, int N) {
    int v = blockIdx.x * blockDim.x + threadIdx.x;
    if (v < N) dis[v] = rsqrtf((float)(deg[v] + 1));
}
__global__ void k_lin1_fb(const float* __restrict__ x, const float* __restrict__ W1,
                          const float* __restrict__ dis, float* __restrict__ hs1,
                          float* __restrict__ agg1, int N) {
    __shared__ float w[64];
    if (threadIdx.x < 64) w[threadIdx.x] = W1[threadIdx.x];
    __syncthreads();
    int v = blockIdx.x * blockDim.x + threadIdx.x;
    if (v >= N) return;
    float4 xv = ((const float4*)x)[v];
    float d = dis[v];
#pragma unroll
    for (int j = 0; j < 16; j++) {
        float h = (xv.x * w[j] + xv.y * w[16 + j] + xv.z * w[32 + j] + xv.w * w[48 + j]) * d;
        hs1[v * 16 + j] = h;
        agg1[v * 16 + j] = h;
    }
}
__global__ void k_scat1_fb(const int* __restrict__ src, const int* __restrict__ dst,
                           const float* __restrict__ hs1, float* __restrict__ agg1, int E4) {
    int t = blockIdx.x * blockDim.x + threadIdx.x;
    if (t >= E4) return;
    int e = t >> 2, q = t & 3;
    int s = src[e], d = dst[e];
    float4 m = ((const float4*)hs1)[s * 4 + q];
    float* a = agg1 + (size_t)d * 16 + q * 4;
    atomicAdd(a + 0, m.x); atomicAdd(a + 1, m.y);
    atomicAdd(a + 2, m.z); atomicAdd(a + 3, m.w);
}
__global__ void k_lin2_fb(const float* __restrict__ agg1, const float* __restrict__ dis,
                          const float* __restrict__ b1, const float* __restrict__ W2,
                          float* __restrict__ hs2, float* __restrict__ agg2, int N) {
    __shared__ float w[32];
    __shared__ float bb[16];
    if (threadIdx.x < 32) w[threadIdx.x] = W2[threadIdx.x];
    if (threadIdx.x < 16) bb[threadIdx.x] = b1[threadIdx.x];
    __syncthreads();
    int v = blockIdx.x * blockDim.x + threadIdx.x;
    if (v >= N) return;
    float d = dis[v];
    float a0 = 0.f, a1 = 0.f;
#pragma unroll
    for (int k = 0; k < 16; k++) {
        float r = fmaxf(agg1[v * 16 + k] * d + bb[k], 0.0f);
        a0 += r * w[k * 2 + 0];
        a1 += r * w[k * 2 + 1];
    }
    float2 hv = make_float2(a0 * d, a1 * d);
    ((float2*)hs2)[v] = hv;
    ((float2*)agg2)[v] = hv;
}
__global__ void k_scat2_fb(const int* __restrict__ src, const int* __restrict__ dst,
                           const float* __restrict__ hs2, float* __restrict__ agg2, int E) {
    int e = blockIdx.x * blockDim.x + threadIdx.x;
    if (e >= E) return;
    int s = src[e], d = dst[e];
    float2 m = ((const float2*)hs2)[s];
    atomicAdd(&agg2[d * 2 + 0], m.x);
    atomicAdd(&agg2[d * 2 + 1], m.y);
}
__global__ void k_out_fb(const float* __restrict__ agg2, const float* __restrict__ dis,
                         const float* __restrict__ b2, float* __restrict__ out, int N) {
    int v = blockIdx.x * blockDim.x + threadIdx.x;
    if (v >= N) return;
    float d = dis[v];
    out[v * 2 + 0] = agg2[v * 2 + 0] * d + b2[0];
    out[v * 2 + 1] = agg2[v * 2 + 1] * d + b2[1];
}

// ---------------- launch ----------------

extern "C" void kernel_launch(void* const* d_in, const int* in_sizes, int n_in,
                              void* d_out, int out_size, void* d_ws, size_t ws_size,
                              hipStream_t stream) {
    const float* x  = (const float*)d_in[0];
    const int*   ei = (const int*)d_in[1];
    const float* W1 = (const float*)d_in[2];
    const float* b1 = (const float*)d_in[3];
    const float* W2 = (const float*)d_in[4];
    const float* b2 = (const float*)d_in[5];

    const int N = in_sizes[0] / 4;
    const int E = in_sizes[1] / 2;
    const int* src = ei;
    const int* dst = ei + E;
    float* outp = (float*)d_out;

    auto align = [](size_t v) { return (v + 255) & ~(size_t)255; };
    const int NBC = (N + CN - 1) >> CSH;   // 98
    const int gN  = (N + TPB - 1) / TPB;
    const int ntiles = (E + STILE - 1) / STILE;   // 782
    const int SD = 8;
    const bool src_fits = (size_t)N <= ((size_t)1 << (32 - CSH));
    const bool fx_safe = (long long)E <= (long long)N * 512;

    auto calc_need = [&](int S1v, int S2v) {
        size_t p1 = (size_t)NBC * S1v * CN * 16;
        size_t p2 = (size_t)NBC * S2v * CN * 8;
        size_t pm = p1 > p2 ? p1 : p2;
        return align((size_t)E * 4)                  /* packed */
             + align((size_t)N * 16)                 /* xs */
             + align((size_t)N * 16)                 /* xse */
             + align((size_t)N * 8)                  /* hs2f */
             + align((size_t)N * 8)                  /* hs2e */
             + align((size_t)N * 4)                  /* deg */
             + align((size_t)ntiles * NBC * 4)       /* chunklT */
             + align((size_t)ntiles * NBC * 4)       /* chunkpT */
             + align(pm);                            /* partial1 / partial2 aliased */
    };

    // preferred config: more splits for occupancy; downgrade if ws is tight
    int S1 = 16, S2 = 32;
    size_t need_new = calc_need(S1, S2);
    if (ws_size < need_new) { S1 = 8; S2 = 16; need_new = calc_need(S1, S2); }

    size_t part_bytes  = (size_t)NBC * S1 * CN * 16;
    size_t part2_bytes = (size_t)NBC * S2 * CN * 8;
    size_t part_max = part_bytes > part2_bytes ? part_bytes : part2_bytes;

    if (ws_size >= need_new && NBC <= NBC_MAX && src_fits && fx_safe) {
        char* ws = (char*)d_ws;
        unsigned* packed = (unsigned*)ws; ws += align((size_t)E * 4);
        float* xs    = (float*)ws;    ws += align((size_t)N * 16);
        unsigned* xse = (unsigned*)ws; ws += align((size_t)N * 16);
        float* hs2f  = (float*)ws;    ws += align((size_t)N * 8);
        unsigned* hs2e = (unsigned*)ws; ws += align((size_t)N * 8);
        int* deg     = (int*)ws;      ws += align((size_t)N * 4);
        int* chunklT = (int*)ws;      ws += align((size_t)ntiles * NBC * 4);
        int* chunkpT = (int*)ws;      ws += align((size_t)ntiles * NBC * 4);
        u64* partial1 = (u64*)ws;
        u64* partial2 = (u64*)ws;     // aliased (partial1 dead by agg2)
        (void)part_max;

        k_zero<<<gN, TPB, 0, stream>>>(deg, N);
        k_passCk<<<ntiles, TPB, 0, stream>>>(src, dst, packed, chunklT, chunkpT, E, NBC, ntiles);
        k_degk<<<NBC * SD, TPB, 0, stream>>>(packed, chunklT, chunkpT, deg, SD, ntiles, E, N);
        k_prepv<<<gN, TPB, 0, stream>>>(x, deg, xs, xse, N);
        k_agg1k<<<NBC * S1, TPB, 0, stream>>>(packed, chunklT, chunkpT, xse, partial1, S1, ntiles, E);
        k_comb1q<<<gN, TPB, 0, stream>>>(partial1, xs, deg, W1, b1, W2, hs2f, hs2e, S1, N);
        k_agg2k<<<NBC * S2, TPB, 0, stream>>>(packed, chunklT, chunkpT, hs2e, partial2, S2, ntiles, E);
        k_comb2q<<<gN, TPB, 0, stream>>>(partial2, hs2f, deg, b2, outp, S2, N);
    } else {
        // fallback: R1 atomic-scatter pipeline
        char* ws = (char*)d_ws;
        int*   deg  = (int*)ws;   ws += align((size_t)N * 4);
        float* dis  = (float*)ws; ws += align((size_t)N * 4);
        float* hs1  = (float*)ws; ws += align((size_t)N * 16 * 4);
        float* agg1 = (float*)ws; ws += align((size_t)N * 16 * 4);
        float* hs2  = (float*)ws; ws += align((size_t)N * 2 * 4);
        float* agg2 = (float*)ws; ws += align((size_t)N * 2 * 4);
        int gE = (E + TPB - 1) / TPB;
        int gE4 = ((size_t)E * 4 + TPB - 1) / TPB;

        k_zero<<<gN, TPB, 0, stream>>>(deg, N);
        k_deg_fb<<<gE, TPB, 0, stream>>>(dst, deg, E);
        k_dis_fb<<<gN, TPB, 0, stream>>>(deg, dis, N);
        k_lin1_fb<<<gN, TPB, 0, stream>>>(x, W1, dis, hs1, agg1, N);
        k_scat1_fb<<<gE4, TPB, 0, stream>>>(src, dst, hs1, agg1, E * 4);
        k_lin2_fb<<<gN, TPB, 0, stream>>>(agg1, dis, b1, W2, hs2, agg2, N);
        k_scat2_fb<<<gE, TPB, 0, stream>>>(src, dst, hs2, agg2, E);
        k_out_fb<<<gN, TPB, 0, stream>>>(agg2, dis, b2, outp, N);
    }
}